// Round 13
// baseline (307.045 us; speedup 1.0000x reference)
//
#include <hip/hip_runtime.h>

namespace {
constexpr int V    = 50000;
constexpr int D    = 50;
constexpr int H    = 50;
constexpr int LDIM = 100;
constexpr int C    = 10;
constexpr int B    = 65536;
constexpr int NPART = (B / 32) * 4;   // 8192 partials (one per wave)

// ---- ws layout (bytes) ----
constexpr size_t OFF_EMB  = 0;                                 // [V][64] bf16
constexpr size_t OFF_TM   = OFF_EMB + (size_t)V * 64 * 2;      // [V][128] fp8 e4m3
constexpr size_t OFF_W1T  = OFF_TM + (size_t)V * 128;          // 2ks*4nt*64l*8e bf16
constexpr size_t OFF_W1B  = OFF_W1T + 2 * 4 * 64 * 8 * 2;
constexpr size_t OFF_WMU  = OFF_W1B + 2 * 4 * 64 * 8 * 2;      // 2ks*7nt*64l*8e bf16
constexpr size_t OFF_B1P  = OFF_WMU + 2 * 7 * 64 * 8 * 2;      // [64] f32
constexpr size_t OFF_BMUP = OFF_B1P + 64 * 4;                  // [128] f32
constexpr size_t OFF_WLSP = OFF_BMUP + 128 * 4;                // [64] f32
constexpr size_t OFF_TT   = OFF_WLSP + 64 * 4;                 // [V] float4 {tlv, exp(-tlv), tmsq, 0}
constexpr size_t OFF_PART = OFF_TT + (size_t)V * 16;           // [NPART] f32
constexpr size_t OFF_CNT  = OFF_PART + (size_t)NPART * 4;      // [1] u32 done-counter
constexpr size_t WS_NEED  = OFF_CNT + 64;

typedef __attribute__((ext_vector_type(8))) short short8;
typedef __attribute__((ext_vector_type(4))) float f32x4;
typedef unsigned long long ull;

__device__ __forceinline__ unsigned short f2bf(float x) {
  unsigned u = __builtin_bit_cast(unsigned, x);
  unsigned r = (u + 0x7FFFu + ((u >> 16) & 1u)) >> 16;  // RNE
  return (unsigned short)r;
}

// ================= preproc (fused): tables + tt + frags =================
__global__ __launch_bounds__(256) void bsg_prep(
    const float* __restrict__ emb, const float* __restrict__ tm,
    const float* __restrict__ tlv, const float* __restrict__ W1,
    const float* __restrict__ Wmu, const float* __restrict__ b1,
    const float* __restrict__ bmu, const float* __restrict__ Wls,
    unsigned short* __restrict__ embB, unsigned char* __restrict__ tmF8,
    float4* __restrict__ tt4, unsigned short* __restrict__ w1t,
    unsigned short* __restrict__ w1b, unsigned short* __restrict__ wmuB,
    float* __restrict__ b1p, float* __restrict__ bmup, float* __restrict__ wlsp,
    unsigned* __restrict__ cnt) {
  const int EMB_T = V * 8;     // chunks of 8 bf16 over [V][64]
  const int TM_T  = V * 8;     // chunks of 16 fp8 over [V][128]
  const int stride = gridDim.x * blockDim.x;
  for (int t = blockIdx.x * blockDim.x + threadIdx.x; t < EMB_T + TM_T; t += stride) {
    if (t < EMB_T) {
      int v = t >> 3, c = t & 7, k0 = c * 8;
      unsigned short r[8];
#pragma unroll
      for (int e = 0; e < 8; ++e) {
        int k = k0 + e;
        r[e] = f2bf(k < D ? emb[(size_t)v * D + k] : 0.f);
      }
      uint4 o;
      o.x = (unsigned)r[0] | ((unsigned)r[1] << 16);
      o.y = (unsigned)r[2] | ((unsigned)r[3] << 16);
      o.z = (unsigned)r[4] | ((unsigned)r[5] << 16);
      o.w = (unsigned)r[6] | ((unsigned)r[7] << 16);
      ((uint4*)(embB + (size_t)v * 64))[c] = o;
    } else {
      int t2 = t - EMB_T;
      int v = t2 >> 3, c = t2 & 7, k0 = c * 16;
      float val[16];
#pragma unroll
      for (int e = 0; e < 16; ++e) {
        int k = k0 + e;
        val[e] = (k < LDIM) ? tm[(size_t)v * LDIM + k] : 0.f;
      }
      uint4 o;
      unsigned dw[4];
      float sq = 0.f;
#pragma unroll
      for (int j = 0; j < 4; ++j) {
        int d = __builtin_amdgcn_cvt_pk_fp8_f32(val[4 * j + 0], val[4 * j + 1], 0, false);
        d = __builtin_amdgcn_cvt_pk_fp8_f32(val[4 * j + 2], val[4 * j + 3], d, true);
        dw[j] = (unsigned)d;
        float q0 = __builtin_amdgcn_cvt_f32_fp8(d, 0);
        float q1 = __builtin_amdgcn_cvt_f32_fp8(d, 1);
        float q2 = __builtin_amdgcn_cvt_f32_fp8(d, 2);
        float q3 = __builtin_amdgcn_cvt_f32_fp8(d, 3);
        sq = fmaf(q0, q0, sq); sq = fmaf(q1, q1, sq);
        sq = fmaf(q2, q2, sq); sq = fmaf(q3, q3, sq);
      }
      o.x = dw[0]; o.y = dw[1]; o.z = dw[2]; o.w = dw[3];
      ((uint4*)(tmF8 + (size_t)v * 128))[c] = o;
#pragma unroll
      for (int off = 1; off < 8; off <<= 1) sq += __shfl_xor(sq, off);
      if (c == 0) {
        float tl = tlv[v];
        float4 q;
        q.x = tl; q.y = __expf(-tl); q.z = sq; q.w = 0.f;
        tt4[v] = q;
      }
    }
  }
  // ---- frags + bias pads + counter reset (block 0 only) ----
  if (blockIdx.x == 0) {
    const int tid = threadIdx.x;
    if (tid == 0) *cnt = 0u;   // reset done-counter every call (graph-replay safe)
    for (int id = tid; id < 1024; id += 256) {
      int half = id >> 9, rem = id & 511;
      int ks = rem >> 8, nt = (rem >> 6) & 3, l = rem & 63;
      unsigned short r[8];
      int n = nt * 16 + (l & 15);
#pragma unroll
      for (int e = 0; e < 8; ++e) {
        int f = ks * 32 + ((l >> 4) << 3) + e;
        float v = (f < D && n < H) ? W1[(size_t)(half * D + f) * H + n] : 0.f;
        r[e] = f2bf(v);
      }
      uint4 o;
      o.x = (unsigned)r[0] | ((unsigned)r[1] << 16);
      o.y = (unsigned)r[2] | ((unsigned)r[3] << 16);
      o.z = (unsigned)r[4] | ((unsigned)r[5] << 16);
      o.w = (unsigned)r[6] | ((unsigned)r[7] << 16);
      unsigned short* dst = half ? w1b : w1t;
      ((uint4*)dst)[(ks * 4 + nt) * 64 + l] = o;
    }
    for (int id = tid; id < 896; id += 256) {
      int ks = id / 448, rem = id % 448;
      int nt = rem >> 6, l = rem & 63;
      unsigned short r[8];
      int n = nt * 16 + (l & 15);
#pragma unroll
      for (int e = 0; e < 8; ++e) {
        int j = ks * 32 + ((l >> 4) << 3) + e;
        float v = (j < H && n < LDIM) ? Wmu[(size_t)j * LDIM + n] : 0.f;
        r[e] = f2bf(v);
      }
      uint4 o;
      o.x = (unsigned)r[0] | ((unsigned)r[1] << 16);
      o.y = (unsigned)r[2] | ((unsigned)r[3] << 16);
      o.z = (unsigned)r[4] | ((unsigned)r[5] << 16);
      o.w = (unsigned)r[6] | ((unsigned)r[7] << 16);
      ((uint4*)wmuB)[(ks * 7 + nt) * 64 + l] = o;
    }
    if (tid < 64)  b1p[tid]  = (tid < H)    ? b1[tid]  : 0.f;
    if (tid < 128) bmup[tid] = (tid < LDIM) ? bmu[tid] : 0.f;
    if (tid < 64)  wlsp[tid] = (tid < H)    ? Wls[tid] : 0.f;
  }
}

// ================== fused main: MLP + KL + final reduce ==================
// LDS = stg only (32 KB) -> 5 blocks/CU. hlds/kb/lptr/mptr OVERLAID into stg
// (lifetime-disjoint with the staging ring; barrier-guarded).
__global__ __launch_bounds__(256, 5) void bsg_main(
    const unsigned short* __restrict__ embB,
    const unsigned char* __restrict__ tmF8, const float4* __restrict__ tt4,
    const unsigned short* __restrict__ w1t,
    const unsigned short* __restrict__ w1b,
    const unsigned short* __restrict__ wmuB,
    const float* __restrict__ b1p, const float* __restrict__ bmup,
    const float* __restrict__ wlsp, const float* __restrict__ bls,
    const int* __restrict__ centers, const int* __restrict__ contexts,
    const int* __restrict__ negctx, float* __restrict__ partials,
    unsigned* __restrict__ cnt, float* __restrict__ out) {
  __shared__ __align__(16) char stg[4][4 * 2048];  // 32 KB total; ring + overlays

  // Overlays (dead while ring is live, and vice versa):
  unsigned short* hlds = (unsigned short*)&stg[0][0];   // [32][64] bf16, bytes [0,4K)
  char* kbbase = &stg[0][4096];                         // kb [2][16][128] fp8, [4K,8K)
  float* lptr = (float*)&stg[1][0];                     // logs partials [2][32], [8K,8.25K)
  float* mptr = (float*)&stg[1][256];                   // musq partials [2][32]

  const int tid = threadIdx.x;
  const int w = tid >> 6, l = tid & 63;
  const int srow = l & 15, kc = l >> 4;
  const int st = w & 1, np = w >> 1;
  const int sblk = blockIdx.x * 32;
  const int sg = sblk + st * 16 + srow;
  const int s3 = srow & 3;

  auto kb_ptr = [&](int st_, int s_, int kbyte) -> char* {
    return kbbase + st_ * 2048 + s_ * 128 + (kbyte ^ ((s_ & 7) << 4));
  };

  char* myl = &stg[w][0];
  const int cofs = ((kc ^ s3) << 4);               // stage src chunk in 64B half
  const int aoff = ((kc ^ s3) << 8) + (srow << 4); // bf16 A-frag read pos (MLP)
  const int rA = ((((kc >> 1) ^ s3) * 16 + srow) * 16) + (kc & 1) * 8;   // fp8 reads (KL)
  const int rB = ((((2 + (kc >> 1)) ^ s3) * 16 + srow) * 16) + (kc & 1) * 8;

  // row ids: 0 = center, 1+c = context c (for this lane's sample)
  int rid[11];
  rid[0] = centers[sg];
#pragma unroll
  for (int c = 0; c < 10; ++c) rid[1 + c] = contexts[sg * 10 + c];

  const short8* w1tF = (const short8*)w1t;
  const short8* w1bF = (const short8*)w1b;

  short8 Bz[2][2], Bt[2][2];
#pragma unroll
  for (int n2 = 0; n2 < 2; ++n2)
#pragma unroll
    for (int ks = 0; ks < 2; ++ks) {
      Bz[n2][ks] = w1bF[(ks * 4 + 2 * np + n2) * 64 + l];
      Bt[n2][ks] = w1tF[(ks * 4 + 2 * np + n2) * 64 + l];
    }
  float b1v[2] = {b1p[(2 * np + 0) * 16 + srow], b1p[(2 * np + 1) * 16 + srow]};

  const unsigned char* embBy = (const unsigned char*)embB;

  f32x4 Z0 = {0.f, 0.f, 0.f, 0.f}, Z1 = {0.f, 0.f, 0.f, 0.f};
  f32x4 hv0 = {0.f, 0.f, 0.f, 0.f}, hv1 = {0.f, 0.f, 0.f, 0.f};

#define MLP_STAGE(T)                                                         \
  do {                                                                       \
    const unsigned char* src_ = embBy + (size_t)rid[(T)] * 128 + cofs;       \
    char* d0_ = myl + ((T) & 3) * 2048;                                      \
    __builtin_amdgcn_global_load_lds(                                        \
        (const __attribute__((address_space(1))) unsigned int*)src_,         \
        (__attribute__((address_space(3))) unsigned int*)d0_, 16, 0, 0);     \
    __builtin_amdgcn_global_load_lds(                                        \
        (const __attribute__((address_space(1))) unsigned int*)(src_ + 64),  \
        (__attribute__((address_space(3))) unsigned int*)(d0_ + 1024),       \
        16, 0, 0);                                                           \
  } while (0)

#define MLP_STEP(T, NW)                                                      \
  do {                                                                       \
    if ((T) + 3 < 11) MLP_STAGE((T) + 3);                                    \
    asm volatile("s_waitcnt vmcnt(" #NW ")" ::: "memory");                   \
    __builtin_amdgcn_sched_barrier(0);                                       \
    const char* sb_ = myl + ((T) & 3) * 2048;                                \
    short8 A0_ = *(const short8*)(sb_ + aoff);                               \
    short8 A1_ = *(const short8*)(sb_ + 1024 + aoff);                        \
    if ((T) == 0) {                                                          \
      Z0 = __builtin_amdgcn_mfma_f32_16x16x32_bf16(A0_, Bz[0][0], Z0, 0, 0, 0); \
      Z0 = __builtin_amdgcn_mfma_f32_16x16x32_bf16(A1_, Bz[0][1], Z0, 0, 0, 0); \
      Z1 = __builtin_amdgcn_mfma_f32_16x16x32_bf16(A0_, Bz[1][0], Z1, 0, 0, 0); \
      Z1 = __builtin_amdgcn_mfma_f32_16x16x32_bf16(A1_, Bz[1][1], Z1, 0, 0, 0); \
    } else {                                                                 \
      f32x4 ac0_ = {0.f, 0.f, 0.f, 0.f}, ac1_ = {0.f, 0.f, 0.f, 0.f};        \
      ac0_ = __builtin_amdgcn_mfma_f32_16x16x32_bf16(A0_, Bt[0][0], ac0_, 0, 0, 0); \
      ac0_ = __builtin_amdgcn_mfma_f32_16x16x32_bf16(A1_, Bt[0][1], ac0_, 0, 0, 0); \
      ac1_ = __builtin_amdgcn_mfma_f32_16x16x32_bf16(A0_, Bt[1][0], ac1_, 0, 0, 0); \
      ac1_ = __builtin_amdgcn_mfma_f32_16x16x32_bf16(A1_, Bt[1][1], ac1_, 0, 0, 0); \
      _Pragma("unroll")                                                      \
      for (int q = 0; q < 4; ++q) {                                          \
        hv0[q] += fmaxf(ac0_[q] + Z0[q] + b1v[0], 0.f);                      \
        hv1[q] += fmaxf(ac1_[q] + Z1[q] + b1v[1], 0.f);                      \
      }                                                                      \
    }                                                                        \
  } while (0)

  MLP_STAGE(0);
  MLP_STAGE(1);
  MLP_STAGE(2);

  MLP_STEP(0, 6); MLP_STEP(1, 6); MLP_STEP(2, 6); MLP_STEP(3, 6);
  MLP_STEP(4, 6); MLP_STEP(5, 6); MLP_STEP(6, 6); MLP_STEP(7, 6);
  MLP_STEP(8, 4); MLP_STEP(9, 2); MLP_STEP(10, 0);

#undef MLP_STEP
#undef MLP_STAGE

  __syncthreads();   // barrier #1: ring dead -> overlays live

  // logs partial from C-fragments (into overlay)
  {
    float wl0 = wlsp[(2 * np + 0) * 16 + srow];
    float wl1 = wlsp[(2 * np + 1) * 16 + srow];
    float lp[4];
#pragma unroll
    for (int q = 0; q < 4; ++q) lp[q] = hv0[q] * wl0 + hv1[q] * wl1;
#pragma unroll
    for (int off = 1; off < 16; off <<= 1)
#pragma unroll
      for (int q = 0; q < 4; ++q) lp[q] += __shfl_xor(lp[q], off);
    if (srow == 0) {
#pragma unroll
      for (int q = 0; q < 4; ++q) lptr[np * 32 + st * 16 + kc * 4 + q] = lp[q];
    }
  }
#pragma unroll
  for (int q = 0; q < 4; ++q) {
    hlds[(st * 16 + kc * 4 + q) * 64 + (2 * np + 0) * 16 + srow] = f2bf(hv0[q]);
    hlds[(st * 16 + kc * 4 + q) * 64 + (2 * np + 1) * 16 + srow] = f2bf(hv1[q]);
  }
  __syncthreads();   // barrier #2

  // zero kb pad region (latents 112..127) — must be after ring is dead
  {
    int st_ = tid >> 7, rem = tid & 127;
    int s_ = rem >> 3, j = rem & 7;
    *(unsigned short*)kb_ptr(st_, s_, 112 + 2 * j) = 0;
  }

  // ---- G3: mu = h @ Wmu + bmu -> quantize fp8 -> kb + musq (from dequant) ----
  {
    const short8* hrow = (const short8*)&hlds[(st * 16 + srow) * 64];
    short8 Ah0 = hrow[kc], Ah1 = hrow[4 + kc];
    const short8* wmF = (const short8*)wmuB;
    f32x4 sqv = {0.f, 0.f, 0.f, 0.f};
    for (int nt = np; nt < 7; nt += 2) {
      short8 B0 = wmF[(0 * 7 + nt) * 64 + l];
      short8 B1 = wmF[(1 * 7 + nt) * 64 + l];
      f32x4 m = {0.f, 0.f, 0.f, 0.f};
      m = __builtin_amdgcn_mfma_f32_16x16x32_bf16(Ah0, B0, m, 0, 0, 0);
      m = __builtin_amdgcn_mfma_f32_16x16x32_bf16(Ah1, B1, m, 0, 0, 0);
      int lcol = nt * 16 + srow;
      float bm = bmup[lcol];
      float mv0 = m[0] + bm, mv1 = m[1] + bm, mv2 = m[2] + bm, mv3 = m[3] + bm;
      int d01 = __builtin_amdgcn_cvt_pk_fp8_f32(mv0, mv1, 0, false);
      int d23 = __builtin_amdgcn_cvt_pk_fp8_f32(mv2, mv3, 0, false);
      float q0 = __builtin_amdgcn_cvt_f32_fp8(d01, 0);
      float q1 = __builtin_amdgcn_cvt_f32_fp8(d01, 1);
      float q2 = __builtin_amdgcn_cvt_f32_fp8(d23, 0);
      float q3 = __builtin_amdgcn_cvt_f32_fp8(d23, 1);
      sqv[0] = fmaf(q0, q0, sqv[0]);
      sqv[1] = fmaf(q1, q1, sqv[1]);
      sqv[2] = fmaf(q2, q2, sqv[2]);
      sqv[3] = fmaf(q3, q3, sqv[3]);
      *(unsigned char*)kb_ptr(st, kc * 4 + 0, lcol) = (unsigned char)(d01 & 0xFF);
      *(unsigned char*)kb_ptr(st, kc * 4 + 1, lcol) = (unsigned char)((d01 >> 8) & 0xFF);
      *(unsigned char*)kb_ptr(st, kc * 4 + 2, lcol) = (unsigned char)(d23 & 0xFF);
      *(unsigned char*)kb_ptr(st, kc * 4 + 3, lcol) = (unsigned char)((d23 >> 8) & 0xFF);
    }
#pragma unroll
    for (int off = 1; off < 16; off <<= 1)
#pragma unroll
      for (int q = 0; q < 4; ++q) sqv[q] += __shfl_xor(sqv[q], off);
    if (srow == 0) {
#pragma unroll
      for (int q = 0; q < 4; ++q) mptr[np * 32 + st * 16 + kc * 4 + q] = sqv[q];
    }
  }
  __syncthreads();   // barrier #3

  // ================= KL phase: wave w -> tile st, parity p=np =================
  const int p = np;
  const int s32 = st * 16 + srow;
  const float lg = bls[0] + lptr[s32] + lptr[32 + s32];
  const float ps = __expf(lg);
  const float msq = mptr[s32] + mptr[32 + s32];
  const bool isdiag = (kc == (srow >> 2));
  const int qd = srow & 3;

  // Bmu from kb (LDS) into registers BEFORE the ring reclaims the overlay bytes
  ull Bmu[4];
#pragma unroll
  for (int ks = 0; ks < 4; ++ks)
    Bmu[ks] = *(const ull*)kb_ptr(st, srow, ks * 32 + kc * 8);

  // 11 rows: center (counted only on p==0), then 5 (ctx,neg) pairs of parity p
  int kidx[11];
  kidx[0] = rid[0];
#pragma unroll
  for (int i = 0; i < 5; ++i) {
    int c = p + 2 * i;
    kidx[1 + 2 * i] = rid[1 + c];
    kidx[2 + 2 * i] = negctx[sg * 10 + c];
  }

  __syncthreads();   // barrier #4: overlay reads complete -> ring may reuse all of stg

  float4 ttb[4];
  float loss = 0.f, klc = 0.f;

#define KL_STAGE(T)                                                          \
  do {                                                                       \
    const unsigned char* src_ = tmF8 + (size_t)kidx[(T)] * 128 + cofs;       \
    char* d0_ = myl + ((T) & 3) * 2048;                                      \
    __builtin_amdgcn_global_load_lds(                                        \
        (const __attribute__((address_space(1))) unsigned int*)src_,         \
        (__attribute__((address_space(3))) unsigned int*)d0_, 16, 0, 0);     \
    __builtin_amdgcn_global_load_lds(                                        \
        (const __attribute__((address_space(1))) unsigned int*)(src_ + 64),  \
        (__attribute__((address_space(3))) unsigned int*)(d0_ + 1024),       \
        16, 0, 0);                                                           \
    ttb[(T) & 3] = tt4[kidx[(T)]];                                           \
  } while (0)

#define KL_STEP(T, NW)                                                       \
  do {                                                                       \
    if ((T) + 3 < 11) KL_STAGE((T) + 3);                                     \
    asm volatile("s_waitcnt vmcnt(" #NW ")" ::: "memory");                   \
    __builtin_amdgcn_sched_barrier(0);                                       \
    const char* kb_ = myl + ((T) & 3) * 2048;                                \
    ull a0_ = *(const ull*)(kb_ + rA);                                       \
    ull a1_ = *(const ull*)(kb_ + rB);                                       \
    ull a2_ = *(const ull*)(kb_ + rA + 1024);                                \
    ull a3_ = *(const ull*)(kb_ + rB + 1024);                                \
    f32x4 acc_ = {0.f, 0.f, 0.f, 0.f};                                       \
    acc_ = __builtin_amdgcn_mfma_f32_16x16x32_fp8_fp8((long)a0_, (long)Bmu[0], acc_, 0, 0, 0); \
    acc_ = __builtin_amdgcn_mfma_f32_16x16x32_fp8_fp8((long)a1_, (long)Bmu[1], acc_, 0, 0, 0); \
    acc_ = __builtin_amdgcn_mfma_f32_16x16x32_fp8_fp8((long)a2_, (long)Bmu[2], acc_, 0, 0, 0); \
    acc_ = __builtin_amdgcn_mfma_f32_16x16x32_fp8_fp8((long)a3_, (long)Bmu[3], acc_, 0, 0, 0); \
    float4 tv_ = ttb[(T) & 3];                                               \
    float dot_ = (qd & 2) ? ((qd & 1) ? acc_[3] : acc_[2])                   \
                          : ((qd & 1) ? acc_[1] : acc_[0]);                  \
    float dsum_ = msq + tv_.z - 2.f * dot_;                                  \
    float kl_ = 0.5f * (fmaf(ps + dsum_, tv_.y, tv_.x - lg) - (float)LDIM);  \
    if ((T) == 0)      loss += (isdiag && p == 0) ? kl_ : 0.f;               \
    else if ((T) & 1)  klc = kl_;                                            \
    else               loss += isdiag ? fmaxf(klc - kl_ + 1.f, 0.f) : 0.f;   \
  } while (0)

  KL_STAGE(0);
  KL_STAGE(1);
  KL_STAGE(2);

  // 3 vmcnt ops per stage (2 gload_lds + 1 tt4 load): steady depth-3 = vmcnt(9)
  KL_STEP(0, 9); KL_STEP(1, 9); KL_STEP(2, 9); KL_STEP(3, 9);
  KL_STEP(4, 9); KL_STEP(5, 9); KL_STEP(6, 9); KL_STEP(7, 9);
  KL_STEP(8, 6); KL_STEP(9, 3); KL_STEP(10, 0);

#undef KL_STEP
#undef KL_STAGE

#pragma unroll
  for (int off = 32; off > 0; off >>= 1) loss += __shfl_down(loss, off);
  if (l == 0) {
    partials[blockIdx.x * 4 + w] = loss;
    __threadfence();   // release: partial visible device-wide before the atomic
  }
  __syncthreads();

  // ---- last-block final reduction (replaces the bsg_reduce launch) ----
  int* flag = (int*)&stg[0][0];   // ring fully dead now
  if (tid == 0) {
    unsigned old = atomicAdd(cnt, 1u);
    *flag = (old == gridDim.x - 1) ? 1 : 0;
  }
  __syncthreads();
  if (*flag) {
    __threadfence();   // acquire: see all blocks' partial stores
    double v = 0.0;
    for (int i = tid; i < NPART; i += 256) v += (double)partials[i];
#pragma unroll
    for (int off = 32; off > 0; off >>= 1) v += __shfl_down(v, off);
    double* ws4 = (double*)&stg[0][64];
    if ((tid & 63) == 0) ws4[tid >> 6] = v;
    __syncthreads();
    if (tid == 0) {
      double t = ws4[0] + ws4[1] + ws4[2] + ws4[3];
      out[0] = (float)(t / (double)B);
    }
  }
}

__global__ __launch_bounds__(256) void bsg_reduce(const float* __restrict__ partials,
                                                  int n, float* __restrict__ out) {
  double v = 0.0;
  for (int i = threadIdx.x; i < n; i += 256) v += (double)partials[i];
#pragma unroll
  for (int off = 32; off > 0; off >>= 1) v += __shfl_down(v, off);
  __shared__ double ws4[4];
  if ((threadIdx.x & 63) == 0) ws4[threadIdx.x >> 6] = v;
  __syncthreads();
  if (threadIdx.x == 0) {
    double t = 0.0;
#pragma unroll
    for (int k = 0; k < 4; ++k) t += ws4[k];
    out[0] = (float)(t / (double)B);
  }
}

// ===================== fallback (R0, known-pass) =====================
__device__ __forceinline__ float kl_term_fb(const float* mu, float ps, float logs,
                                            int idx, const float* tm_tbl,
                                            const float* tlv_tbl) {
  const float* tm = tm_tbl + (size_t)idx * LDIM;
  float tlv = tlv_tbl[idx];
  float d0 = 0.f, d1 = 0.f, d2 = 0.f, d3 = 0.f;
#pragma unroll
  for (int l = 0; l < LDIM; l += 4) {
    float4 t = *reinterpret_cast<const float4*>(tm + l);
    float a0 = mu[l] - t.x, a1 = mu[l + 1] - t.y;
    float a2 = mu[l + 2] - t.z, a3 = mu[l + 3] - t.w;
    d0 = fmaf(a0, a0, d0); d1 = fmaf(a1, a1, d1);
    d2 = fmaf(a2, a2, d2); d3 = fmaf(a3, a3, d3);
  }
  return 0.5f * (fmaf(ps + (d0 + d1) + (d2 + d3), __expf(-tlv), tlv - logs) - (float)LDIM);
}

__global__ __launch_bounds__(256) void bsg_fb(
    const float* __restrict__ emb, const float* __restrict__ W1,
    const float* __restrict__ b1, const float* __restrict__ Wmu,
    const float* __restrict__ bmu, const float* __restrict__ Wls,
    const float* __restrict__ bls, const float* __restrict__ tm_tbl,
    const float* __restrict__ tlv_tbl, const int* __restrict__ centers,
    const int* __restrict__ contexts, const int* __restrict__ negctx,
    float* __restrict__ partials) {
  const int b = blockIdx.x * 256 + threadIdx.x;
  const int cen = centers[b];
  float ecen[D];
  const float* ep = emb + (size_t)cen * D;
#pragma unroll
  for (int f = 0; f < D; f += 2) {
    float2 v = *reinterpret_cast<const float2*>(ep + f);
    ecen[f] = v.x; ecen[f + 1] = v.y;
  }
  float z[H];
#pragma unroll
  for (int j = 0; j < H; ++j) z[j] = b1[j];
#pragma unroll
  for (int f = 0; f < D; ++f) {
    float vf = ecen[f];
#pragma unroll
    for (int j = 0; j < H; ++j) z[j] = fmaf(vf, W1[(D + f) * H + j], z[j]);
  }
  float h[H];
#pragma unroll
  for (int j = 0; j < H; ++j) h[j] = 0.f;
  for (int c = 0; c < C; ++c) {
    const float* ecp = emb + (size_t)contexts[b * C + c] * D;
    float s[H];
#pragma unroll
    for (int j = 0; j < H; ++j) s[j] = z[j];
#pragma unroll
    for (int f = 0; f < D; ++f) {
      float vf = ecp[f];
#pragma unroll
      for (int j = 0; j < H; ++j) s[j] = fmaf(vf, W1[f * H + j], s[j]);
    }
#pragma unroll
    for (int j = 0; j < H; ++j) h[j] += fmaxf(s[j], 0.f);
  }
  float mu[LDIM];
#pragma unroll
  for (int l = 0; l < LDIM; ++l) mu[l] = bmu[l];
#pragma unroll
  for (int j = 0; j < H; ++j) {
    float hj = h[j];
#pragma unroll
    for (int l = 0; l < LDIM; ++l) mu[l] = fmaf(hj, Wmu[j * LDIM + l], mu[l]);
  }
  float logs = bls[0];
#pragma unroll
  for (int j = 0; j < H; ++j) logs = fmaf(h[j], Wls[j], logs);
  float ps = __expf(logs);
  float acc = kl_term_fb(mu, ps, logs, cen, tm_tbl, tlv_tbl);
  for (int c = 0; c < C; ++c) {
    float kc = kl_term_fb(mu, ps, logs, contexts[b * C + c], tm_tbl, tlv_tbl);
    float kn = kl_term_fb(mu, ps, logs, negctx[b * C + c], tm_tbl, tlv_tbl);
    acc += fmaxf(kc - kn + 1.f, 0.f);
  }
  float vs = acc;
#pragma unroll
  for (int off = 32; off > 0; off >>= 1) vs += __shfl_down(vs, off);
  __shared__ float wsum[4];
  if ((threadIdx.x & 63) == 0) wsum[threadIdx.x >> 6] = vs;
  __syncthreads();
  if (threadIdx.x == 0) {
    float t = 0.f;
#pragma unroll
    for (int k = 0; k < 4; ++k) t += wsum[k];
    partials[blockIdx.x] = t;
  }
}
}  // namespace

extern "C" void kernel_launch(void* const* d_in, const int* in_sizes, int n_in,
                              void* d_out, int out_size, void* d_ws, size_t ws_size,
                              hipStream_t stream) {
  const float* emb     = (const float*)d_in[0];
  const float* W1      = (const float*)d_in[1];
  const float* b1      = (const float*)d_in[2];
  const float* Wmu     = (const float*)d_in[3];
  const float* bmu     = (const float*)d_in[4];
  const float* Wls     = (const float*)d_in[5];
  const float* bls     = (const float*)d_in[6];
  const float* tm      = (const float*)d_in[7];
  const float* tlv     = (const float*)d_in[8];
  const int*   centers = (const int*)d_in[9];
  const int*   ctx     = (const int*)d_in[10];
  const int*   negc    = (const int*)d_in[11];
  float* out = (float*)d_out;

  if (ws_size < WS_NEED + 1024) {
    float* partials = (float*)d_ws;
    bsg_fb<<<256, 256, 0, stream>>>(emb, W1, b1, Wmu, bmu, Wls, bls, tm, tlv,
                                    centers, ctx, negc, partials);
    bsg_reduce<<<1, 256, 0, stream>>>(partials, 256, out);
    return;
  }

  char* ws = (char*)d_ws;
  unsigned short* embB = (unsigned short*)(ws + OFF_EMB);
  unsigned char*  tmF8 = (unsigned char*)(ws + OFF_TM);
  unsigned short* w1t  = (unsigned short*)(ws + OFF_W1T);
  unsigned short* w1b  = (unsigned short*)(ws + OFF_W1B);
  unsigned short* wmuB = (unsigned short*)(ws + OFF_WMU);
  float* b1p  = (float*)(ws + OFF_B1P);
  float* bmup = (float*)(ws + OFF_BMUP);
  float* wlsp = (float*)(ws + OFF_WLSP);
  float4* tt4 = (float4*)(ws + OFF_TT);
  float* partials = (float*)(ws + OFF_PART);
  unsigned* cnt = (unsigned*)(ws + OFF_CNT);

  bsg_prep<<<1024, 256, 0, stream>>>(emb, tm, tlv, W1, Wmu, b1, bmu, Wls,
                                     embB, tmF8, tt4, w1t, w1b, wmuB, b1p, bmup,
                                     wlsp, cnt);
  bsg_main<<<B / 32, 256, 0, stream>>>(embB, tmF8, tt4, w1t, w1b, wmuB,
                                       b1p, bmup, wlsp, bls, centers, ctx, negc,
                                       partials, cnt, out);
}

// Round 14
// 302.603 us; speedup vs baseline: 1.0147x; 1.0147x over previous
//
#include <hip/hip_runtime.h>

namespace {
constexpr int V    = 50000;
constexpr int D    = 50;
constexpr int H    = 50;
constexpr int LDIM = 100;
constexpr int C    = 10;
constexpr int B    = 65536;
constexpr int NPART = (B / 32) * 4;   // 8192 partials (one per wave)

// ---- ws layout (bytes) ----
constexpr size_t OFF_EMB  = 0;                                 // [V][64] bf16
constexpr size_t OFF_TM   = OFF_EMB + (size_t)V * 64 * 2;      // [V][128] fp8 e4m3
constexpr size_t OFF_W1T  = OFF_TM + (size_t)V * 128;          // 2ks*4nt*64l*8e bf16
constexpr size_t OFF_W1B  = OFF_W1T + 2 * 4 * 64 * 8 * 2;
constexpr size_t OFF_WMU  = OFF_W1B + 2 * 4 * 64 * 8 * 2;      // 2ks*7nt*64l*8e bf16
constexpr size_t OFF_B1P  = OFF_WMU + 2 * 7 * 64 * 8 * 2;      // [64] f32
constexpr size_t OFF_BMUP = OFF_B1P + 64 * 4;                  // [128] f32
constexpr size_t OFF_WLSP = OFF_BMUP + 128 * 4;                // [64] f32
constexpr size_t OFF_TT   = OFF_WLSP + 64 * 4;                 // [V] float4 {tlv, exp(-tlv), tmsq, 0}
constexpr size_t OFF_PART = OFF_TT + (size_t)V * 16;           // [NPART] f32
constexpr size_t OFF_CNT  = OFF_PART + (size_t)NPART * 4;      // [1] u32 done-counter
constexpr size_t WS_NEED  = OFF_CNT + 64;

typedef __attribute__((ext_vector_type(8))) short short8;
typedef __attribute__((ext_vector_type(4))) float f32x4;
typedef unsigned long long ull;

__device__ __forceinline__ unsigned short f2bf(float x) {
  unsigned u = __builtin_bit_cast(unsigned, x);
  unsigned r = (u + 0x7FFFu + ((u >> 16) & 1u)) >> 16;  // RNE
  return (unsigned short)r;
}

// ================= preproc (fused): tables + tt + frags =================
__global__ __launch_bounds__(256) void bsg_prep(
    const float* __restrict__ emb, const float* __restrict__ tm,
    const float* __restrict__ tlv, const float* __restrict__ W1,
    const float* __restrict__ Wmu, const float* __restrict__ b1,
    const float* __restrict__ bmu, const float* __restrict__ Wls,
    unsigned short* __restrict__ embB, unsigned char* __restrict__ tmF8,
    float4* __restrict__ tt4, unsigned short* __restrict__ w1t,
    unsigned short* __restrict__ w1b, unsigned short* __restrict__ wmuB,
    float* __restrict__ b1p, float* __restrict__ bmup, float* __restrict__ wlsp,
    unsigned* __restrict__ cnt) {
  const int EMB_T = V * 8;     // chunks of 8 bf16 over [V][64]
  const int TM_T  = V * 8;     // chunks of 16 fp8 over [V][128]
  const int stride = gridDim.x * blockDim.x;
  for (int t = blockIdx.x * blockDim.x + threadIdx.x; t < EMB_T + TM_T; t += stride) {
    if (t < EMB_T) {
      int v = t >> 3, c = t & 7, k0 = c * 8;
      unsigned short r[8];
#pragma unroll
      for (int e = 0; e < 8; ++e) {
        int k = k0 + e;
        r[e] = f2bf(k < D ? emb[(size_t)v * D + k] : 0.f);
      }
      uint4 o;
      o.x = (unsigned)r[0] | ((unsigned)r[1] << 16);
      o.y = (unsigned)r[2] | ((unsigned)r[3] << 16);
      o.z = (unsigned)r[4] | ((unsigned)r[5] << 16);
      o.w = (unsigned)r[6] | ((unsigned)r[7] << 16);
      ((uint4*)(embB + (size_t)v * 64))[c] = o;
    } else {
      int t2 = t - EMB_T;
      int v = t2 >> 3, c = t2 & 7, k0 = c * 16;
      float val[16];
#pragma unroll
      for (int e = 0; e < 16; ++e) {
        int k = k0 + e;
        val[e] = (k < LDIM) ? tm[(size_t)v * LDIM + k] : 0.f;
      }
      uint4 o;
      unsigned dw[4];
      float sq = 0.f;
#pragma unroll
      for (int j = 0; j < 4; ++j) {
        int d = __builtin_amdgcn_cvt_pk_fp8_f32(val[4 * j + 0], val[4 * j + 1], 0, false);
        d = __builtin_amdgcn_cvt_pk_fp8_f32(val[4 * j + 2], val[4 * j + 3], d, true);
        dw[j] = (unsigned)d;
        float q0 = __builtin_amdgcn_cvt_f32_fp8(d, 0);
        float q1 = __builtin_amdgcn_cvt_f32_fp8(d, 1);
        float q2 = __builtin_amdgcn_cvt_f32_fp8(d, 2);
        float q3 = __builtin_amdgcn_cvt_f32_fp8(d, 3);
        sq = fmaf(q0, q0, sq); sq = fmaf(q1, q1, sq);
        sq = fmaf(q2, q2, sq); sq = fmaf(q3, q3, sq);
      }
      o.x = dw[0]; o.y = dw[1]; o.z = dw[2]; o.w = dw[3];
      ((uint4*)(tmF8 + (size_t)v * 128))[c] = o;
#pragma unroll
      for (int off = 1; off < 8; off <<= 1) sq += __shfl_xor(sq, off);
      if (c == 0) {
        float tl = tlv[v];
        float4 q;
        q.x = tl; q.y = __expf(-tl); q.z = sq; q.w = 0.f;
        tt4[v] = q;
      }
    }
  }
  // ---- frags + bias pads + counter reset (block 0 only) ----
  if (blockIdx.x == 0) {
    const int tid = threadIdx.x;
    if (tid == 0) *cnt = 0u;   // reset done-counter every call (graph-replay safe)
    for (int id = tid; id < 1024; id += 256) {
      int half = id >> 9, rem = id & 511;
      int ks = rem >> 8, nt = (rem >> 6) & 3, l = rem & 63;
      unsigned short r[8];
      int n = nt * 16 + (l & 15);
#pragma unroll
      for (int e = 0; e < 8; ++e) {
        int f = ks * 32 + ((l >> 4) << 3) + e;
        float v = (f < D && n < H) ? W1[(size_t)(half * D + f) * H + n] : 0.f;
        r[e] = f2bf(v);
      }
      uint4 o;
      o.x = (unsigned)r[0] | ((unsigned)r[1] << 16);
      o.y = (unsigned)r[2] | ((unsigned)r[3] << 16);
      o.z = (unsigned)r[4] | ((unsigned)r[5] << 16);
      o.w = (unsigned)r[6] | ((unsigned)r[7] << 16);
      unsigned short* dst = half ? w1b : w1t;
      ((uint4*)dst)[(ks * 4 + nt) * 64 + l] = o;
    }
    for (int id = tid; id < 896; id += 256) {
      int ks = id / 448, rem = id % 448;
      int nt = rem >> 6, l = rem & 63;
      unsigned short r[8];
      int n = nt * 16 + (l & 15);
#pragma unroll
      for (int e = 0; e < 8; ++e) {
        int j = ks * 32 + ((l >> 4) << 3) + e;
        float v = (j < H && n < LDIM) ? Wmu[(size_t)j * LDIM + n] : 0.f;
        r[e] = f2bf(v);
      }
      uint4 o;
      o.x = (unsigned)r[0] | ((unsigned)r[1] << 16);
      o.y = (unsigned)r[2] | ((unsigned)r[3] << 16);
      o.z = (unsigned)r[4] | ((unsigned)r[5] << 16);
      o.w = (unsigned)r[6] | ((unsigned)r[7] << 16);
      ((uint4*)wmuB)[(ks * 7 + nt) * 64 + l] = o;
    }
    if (tid < 64)  b1p[tid]  = (tid < H)    ? b1[tid]  : 0.f;
    if (tid < 128) bmup[tid] = (tid < LDIM) ? bmu[tid] : 0.f;
    if (tid < 64)  wlsp[tid] = (tid < H)    ? Wls[tid] : 0.f;
  }
}

// ================== fused main: MLP + KL + final reduce ==================
// R12 structure exactly (40 KB LDS, (256,4) -> VGPR cap 128, no spill).
// Deltas vs R12: KL steady vmcnt(9) (3 ops/stage), last-block reduce fused.
__global__ __launch_bounds__(256, 4) void bsg_main(
    const unsigned short* __restrict__ embB,
    const unsigned char* __restrict__ tmF8, const float4* __restrict__ tt4,
    const unsigned short* __restrict__ w1t,
    const unsigned short* __restrict__ w1b,
    const unsigned short* __restrict__ wmuB,
    const float* __restrict__ b1p, const float* __restrict__ bmup,
    const float* __restrict__ wlsp, const float* __restrict__ bls,
    const int* __restrict__ centers, const int* __restrict__ contexts,
    const int* __restrict__ negctx, float* __restrict__ partials,
    unsigned* __restrict__ cnt, float* __restrict__ out) {
  __shared__ __align__(16) char stg[4][4 * 2048];  // per-wave 4-slot staging ring (32 KB)
  __shared__ unsigned short hlds[32][64];          // h, bf16 (4 KB)
  __shared__ unsigned char kb[2][16][128];         // mu fp8, XOR-swizzled (4 KB)

  float* lptr = (float*)&stg[0][0];    // overlay: logs partials [2][32]  (256 B)
  float* mptr = (float*)&stg[0][256];  // overlay: musq partials [2][32]  (256 B)

  const int tid = threadIdx.x;
  const int w = tid >> 6, l = tid & 63;
  const int srow = l & 15, kc = l >> 4;
  const int st = w & 1, np = w >> 1;
  const int sblk = blockIdx.x * 32;
  const int sg = sblk + st * 16 + srow;
  const int s3 = srow & 3;

  char* kbbase = (char*)&kb[0][0][0];
  auto kb_ptr = [&](int st_, int s_, int kbyte) -> char* {
    return kbbase + st_ * 2048 + s_ * 128 + (kbyte ^ ((s_ & 7) << 4));
  };

  // zero kb pad region (latents 112..127)
  {
    int st_ = tid >> 7, rem = tid & 127;
    int s_ = rem >> 3, j = rem & 7;
    *(unsigned short*)kb_ptr(st_, s_, 112 + 2 * j) = 0;
  }

  char* myl = &stg[w][0];
  const int cofs = ((kc ^ s3) << 4);               // stage src chunk in 64B half
  const int aoff = ((kc ^ s3) << 8) + (srow << 4); // bf16 A-frag read pos (MLP)
  const int rA = ((((kc >> 1) ^ s3) * 16 + srow) * 16) + (kc & 1) * 8;   // fp8 reads (KL)
  const int rB = ((((2 + (kc >> 1)) ^ s3) * 16 + srow) * 16) + (kc & 1) * 8;

  // row ids: 0 = center, 1+c = context c (for this lane's sample)
  int rid[11];
  rid[0] = centers[sg];
#pragma unroll
  for (int c = 0; c < 10; ++c) rid[1 + c] = contexts[sg * 10 + c];

  const short8* w1tF = (const short8*)w1t;
  const short8* w1bF = (const short8*)w1b;

  short8 Bz[2][2], Bt[2][2];
#pragma unroll
  for (int n2 = 0; n2 < 2; ++n2)
#pragma unroll
    for (int ks = 0; ks < 2; ++ks) {
      Bz[n2][ks] = w1bF[(ks * 4 + 2 * np + n2) * 64 + l];
      Bt[n2][ks] = w1tF[(ks * 4 + 2 * np + n2) * 64 + l];
    }
  float b1v[2] = {b1p[(2 * np + 0) * 16 + srow], b1p[(2 * np + 1) * 16 + srow]};

  const unsigned char* embBy = (const unsigned char*)embB;

  f32x4 Z0 = {0.f, 0.f, 0.f, 0.f}, Z1 = {0.f, 0.f, 0.f, 0.f};
  f32x4 hv0 = {0.f, 0.f, 0.f, 0.f}, hv1 = {0.f, 0.f, 0.f, 0.f};

#define MLP_STAGE(T)                                                         \
  do {                                                                       \
    const unsigned char* src_ = embBy + (size_t)rid[(T)] * 128 + cofs;       \
    char* d0_ = myl + ((T) & 3) * 2048;                                      \
    __builtin_amdgcn_global_load_lds(                                        \
        (const __attribute__((address_space(1))) unsigned int*)src_,         \
        (__attribute__((address_space(3))) unsigned int*)d0_, 16, 0, 0);     \
    __builtin_amdgcn_global_load_lds(                                        \
        (const __attribute__((address_space(1))) unsigned int*)(src_ + 64),  \
        (__attribute__((address_space(3))) unsigned int*)(d0_ + 1024),       \
        16, 0, 0);                                                           \
  } while (0)

#define MLP_STEP(T, NW)                                                      \
  do {                                                                       \
    if ((T) + 3 < 11) MLP_STAGE((T) + 3);                                    \
    asm volatile("s_waitcnt vmcnt(" #NW ")" ::: "memory");                   \
    __builtin_amdgcn_sched_barrier(0);                                       \
    const char* sb_ = myl + ((T) & 3) * 2048;                                \
    short8 A0_ = *(const short8*)(sb_ + aoff);                               \
    short8 A1_ = *(const short8*)(sb_ + 1024 + aoff);                        \
    if ((T) == 0) {                                                          \
      Z0 = __builtin_amdgcn_mfma_f32_16x16x32_bf16(A0_, Bz[0][0], Z0, 0, 0, 0); \
      Z0 = __builtin_amdgcn_mfma_f32_16x16x32_bf16(A1_, Bz[0][1], Z0, 0, 0, 0); \
      Z1 = __builtin_amdgcn_mfma_f32_16x16x32_bf16(A0_, Bz[1][0], Z1, 0, 0, 0); \
      Z1 = __builtin_amdgcn_mfma_f32_16x16x32_bf16(A1_, Bz[1][1], Z1, 0, 0, 0); \
    } else {                                                                 \
      f32x4 ac0_ = {0.f, 0.f, 0.f, 0.f}, ac1_ = {0.f, 0.f, 0.f, 0.f};        \
      ac0_ = __builtin_amdgcn_mfma_f32_16x16x32_bf16(A0_, Bt[0][0], ac0_, 0, 0, 0); \
      ac0_ = __builtin_amdgcn_mfma_f32_16x16x32_bf16(A1_, Bt[0][1], ac0_, 0, 0, 0); \
      ac1_ = __builtin_amdgcn_mfma_f32_16x16x32_bf16(A0_, Bt[1][0], ac1_, 0, 0, 0); \
      ac1_ = __builtin_amdgcn_mfma_f32_16x16x32_bf16(A1_, Bt[1][1], ac1_, 0, 0, 0); \
      _Pragma("unroll")                                                      \
      for (int q = 0; q < 4; ++q) {                                          \
        hv0[q] += fmaxf(ac0_[q] + Z0[q] + b1v[0], 0.f);                      \
        hv1[q] += fmaxf(ac1_[q] + Z1[q] + b1v[1], 0.f);                      \
      }                                                                      \
    }                                                                        \
  } while (0)

  MLP_STAGE(0);
  MLP_STAGE(1);
  MLP_STAGE(2);

  MLP_STEP(0, 6); MLP_STEP(1, 6); MLP_STEP(2, 6); MLP_STEP(3, 6);
  MLP_STEP(4, 6); MLP_STEP(5, 6); MLP_STEP(6, 6); MLP_STEP(7, 6);
  MLP_STEP(8, 4); MLP_STEP(9, 2); MLP_STEP(10, 0);

#undef MLP_STEP
#undef MLP_STAGE

  __syncthreads();   // all waves done with stg -> overlay region writable

  // logs partial from C-fragments (into overlay)
  {
    float wl0 = wlsp[(2 * np + 0) * 16 + srow];
    float wl1 = wlsp[(2 * np + 1) * 16 + srow];
    float lp[4];
#pragma unroll
    for (int q = 0; q < 4; ++q) lp[q] = hv0[q] * wl0 + hv1[q] * wl1;
#pragma unroll
    for (int off = 1; off < 16; off <<= 1)
#pragma unroll
      for (int q = 0; q < 4; ++q) lp[q] += __shfl_xor(lp[q], off);
    if (srow == 0) {
#pragma unroll
      for (int q = 0; q < 4; ++q) lptr[np * 32 + st * 16 + kc * 4 + q] = lp[q];
    }
  }
#pragma unroll
  for (int q = 0; q < 4; ++q) {
    hlds[st * 16 + kc * 4 + q][(2 * np + 0) * 16 + srow] = f2bf(hv0[q]);
    hlds[st * 16 + kc * 4 + q][(2 * np + 1) * 16 + srow] = f2bf(hv1[q]);
  }
  __syncthreads();

  // ---- G3: mu = h @ Wmu + bmu -> quantize fp8 -> kb + musq (from dequant) ----
  {
    const short8* hrow = (const short8*)&hlds[st * 16 + srow][0];
    short8 Ah0 = hrow[kc], Ah1 = hrow[4 + kc];
    const short8* wmF = (const short8*)wmuB;
    f32x4 sqv = {0.f, 0.f, 0.f, 0.f};
    for (int nt = np; nt < 7; nt += 2) {
      short8 B0 = wmF[(0 * 7 + nt) * 64 + l];
      short8 B1 = wmF[(1 * 7 + nt) * 64 + l];
      f32x4 m = {0.f, 0.f, 0.f, 0.f};
      m = __builtin_amdgcn_mfma_f32_16x16x32_bf16(Ah0, B0, m, 0, 0, 0);
      m = __builtin_amdgcn_mfma_f32_16x16x32_bf16(Ah1, B1, m, 0, 0, 0);
      int lcol = nt * 16 + srow;
      float bm = bmup[lcol];
      float mv0 = m[0] + bm, mv1 = m[1] + bm, mv2 = m[2] + bm, mv3 = m[3] + bm;
      int d01 = __builtin_amdgcn_cvt_pk_fp8_f32(mv0, mv1, 0, false);
      int d23 = __builtin_amdgcn_cvt_pk_fp8_f32(mv2, mv3, 0, false);
      float q0 = __builtin_amdgcn_cvt_f32_fp8(d01, 0);
      float q1 = __builtin_amdgcn_cvt_f32_fp8(d01, 1);
      float q2 = __builtin_amdgcn_cvt_f32_fp8(d23, 0);
      float q3 = __builtin_amdgcn_cvt_f32_fp8(d23, 1);
      sqv[0] = fmaf(q0, q0, sqv[0]);
      sqv[1] = fmaf(q1, q1, sqv[1]);
      sqv[2] = fmaf(q2, q2, sqv[2]);
      sqv[3] = fmaf(q3, q3, sqv[3]);
      *(unsigned char*)kb_ptr(st, kc * 4 + 0, lcol) = (unsigned char)(d01 & 0xFF);
      *(unsigned char*)kb_ptr(st, kc * 4 + 1, lcol) = (unsigned char)((d01 >> 8) & 0xFF);
      *(unsigned char*)kb_ptr(st, kc * 4 + 2, lcol) = (unsigned char)(d23 & 0xFF);
      *(unsigned char*)kb_ptr(st, kc * 4 + 3, lcol) = (unsigned char)((d23 >> 8) & 0xFF);
    }
#pragma unroll
    for (int off = 1; off < 16; off <<= 1)
#pragma unroll
      for (int q = 0; q < 4; ++q) sqv[q] += __shfl_xor(sqv[q], off);
    if (srow == 0) {
#pragma unroll
      for (int q = 0; q < 4; ++q) mptr[np * 32 + st * 16 + kc * 4 + q] = sqv[q];
    }
  }
  __syncthreads();

  // ================= KL phase: wave w -> tile st, parity p=np =================
  const int p = np;
  const int s32 = st * 16 + srow;
  const float lg = bls[0] + lptr[s32] + lptr[32 + s32];
  const float ps = __expf(lg);
  const float msq = mptr[s32] + mptr[32 + s32];
  const bool isdiag = (kc == (srow >> 2));
  const int qd = srow & 3;

  // Bmu from kb (LDS)
  ull Bmu[4];
#pragma unroll
  for (int ks = 0; ks < 4; ++ks)
    Bmu[ks] = *(const ull*)kb_ptr(st, srow, ks * 32 + kc * 8);

  // 11 rows: center (counted only on p==0), then 5 (ctx,neg) pairs of parity p
  int kidx[11];
  kidx[0] = rid[0];
#pragma unroll
  for (int i = 0; i < 5; ++i) {
    int c = p + 2 * i;
    kidx[1 + 2 * i] = rid[1 + c];
    kidx[2 + 2 * i] = negctx[sg * 10 + c];
  }

  __syncthreads();   // overlay reads complete (barrier drains lgkmcnt) before stg reuse

  float4 ttb[4];
  float loss = 0.f, klc = 0.f;

#define KL_STAGE(T)                                                          \
  do {                                                                       \
    const unsigned char* src_ = tmF8 + (size_t)kidx[(T)] * 128 + cofs;       \
    char* d0_ = myl + ((T) & 3) * 2048;                                      \
    __builtin_amdgcn_global_load_lds(                                        \
        (const __attribute__((address_space(1))) unsigned int*)src_,         \
        (__attribute__((address_space(3))) unsigned int*)d0_, 16, 0, 0);     \
    __builtin_amdgcn_global_load_lds(                                        \
        (const __attribute__((address_space(1))) unsigned int*)(src_ + 64),  \
        (__attribute__((address_space(3))) unsigned int*)(d0_ + 1024),       \
        16, 0, 0);                                                           \
    ttb[(T) & 3] = tt4[kidx[(T)]];                                           \
  } while (0)

#define KL_STEP(T, NW)                                                       \
  do {                                                                       \
    if ((T) + 3 < 11) KL_STAGE((T) + 3);                                     \
    asm volatile("s_waitcnt vmcnt(" #NW ")" ::: "memory");                   \
    __builtin_amdgcn_sched_barrier(0);                                       \
    const char* kb_ = myl + ((T) & 3) * 2048;                                \
    ull a0_ = *(const ull*)(kb_ + rA);                                       \
    ull a1_ = *(const ull*)(kb_ + rB);                                       \
    ull a2_ = *(const ull*)(kb_ + rA + 1024);                                \
    ull a3_ = *(const ull*)(kb_ + rB + 1024);                                \
    f32x4 acc_ = {0.f, 0.f, 0.f, 0.f};                                       \
    acc_ = __builtin_amdgcn_mfma_f32_16x16x32_fp8_fp8((long)a0_, (long)Bmu[0], acc_, 0, 0, 0); \
    acc_ = __builtin_amdgcn_mfma_f32_16x16x32_fp8_fp8((long)a1_, (long)Bmu[1], acc_, 0, 0, 0); \
    acc_ = __builtin_amdgcn_mfma_f32_16x16x32_fp8_fp8((long)a2_, (long)Bmu[2], acc_, 0, 0, 0); \
    acc_ = __builtin_amdgcn_mfma_f32_16x16x32_fp8_fp8((long)a3_, (long)Bmu[3], acc_, 0, 0, 0); \
    float4 tv_ = ttb[(T) & 3];                                               \
    float dot_ = (qd & 2) ? ((qd & 1) ? acc_[3] : acc_[2])                   \
                          : ((qd & 1) ? acc_[1] : acc_[0]);                  \
    float dsum_ = msq + tv_.z - 2.f * dot_;                                  \
    float kl_ = 0.5f * (fmaf(ps + dsum_, tv_.y, tv_.x - lg) - (float)LDIM);  \
    if ((T) == 0)      loss += (isdiag && p == 0) ? kl_ : 0.f;               \
    else if ((T) & 1)  klc = kl_;                                            \
    else               loss += isdiag ? fmaxf(klc - kl_ + 1.f, 0.f) : 0.f;   \
  } while (0)

  KL_STAGE(0);
  KL_STAGE(1);
  KL_STAGE(2);

  // 3 vmcnt ops per stage (2 gload_lds + 1 tt4 load): steady depth-3 = vmcnt(9)
  KL_STEP(0, 9); KL_STEP(1, 9); KL_STEP(2, 9); KL_STEP(3, 9);
  KL_STEP(4, 9); KL_STEP(5, 9); KL_STEP(6, 9); KL_STEP(7, 9);
  KL_STEP(8, 6); KL_STEP(9, 3); KL_STEP(10, 0);

#undef KL_STEP
#undef KL_STAGE

#pragma unroll
  for (int off = 32; off > 0; off >>= 1) loss += __shfl_down(loss, off);
  if (l == 0) {
    partials[blockIdx.x * 4 + w] = loss;
    __threadfence();   // release: partial visible device-wide before the atomic
  }
  __syncthreads();

  // ---- last-block final reduction (replaces the bsg_reduce launch) ----
  int* flag = (int*)&stg[0][0];   // ring fully dead now
  if (tid == 0) {
    unsigned old = atomicAdd(cnt, 1u);
    *flag = (old == gridDim.x - 1) ? 1 : 0;
  }
  __syncthreads();
  if (*flag) {
    __threadfence();   // acquire: see all blocks' partial stores
    double v = 0.0;
    for (int i = tid; i < NPART; i += 256) v += (double)partials[i];
#pragma unroll
    for (int off = 32; off > 0; off >>= 1) v += __shfl_down(v, off);
    double* ws4 = (double*)&stg[0][64];
    if ((tid & 63) == 0) ws4[tid >> 6] = v;
    __syncthreads();
    if (tid == 0) {
      double t = ws4[0] + ws4[1] + ws4[2] + ws4[3];
      out[0] = (float)(t / (double)B);
    }
  }
}

__global__ __launch_bounds__(256) void bsg_reduce(const float* __restrict__ partials,
                                                  int n, float* __restrict__ out) {
  double v = 0.0;
  for (int i = threadIdx.x; i < n; i += 256) v += (double)partials[i];
#pragma unroll
  for (int off = 32; off > 0; off >>= 1) v += __shfl_down(v, off);
  __shared__ double ws4[4];
  if ((threadIdx.x & 63) == 0) ws4[threadIdx.x >> 6] = v;
  __syncthreads();
  if (threadIdx.x == 0) {
    double t = 0.0;
#pragma unroll
    for (int k = 0; k < 4; ++k) t += ws4[k];
    out[0] = (float)(t / (double)B);
  }
}

// ===================== fallback (R0, known-pass) =====================
__device__ __forceinline__ float kl_term_fb(const float* mu, float ps, float logs,
                                            int idx, const float* tm_tbl,
                                            const float* tlv_tbl) {
  const float* tm = tm_tbl + (size_t)idx * LDIM;
  float tlv = tlv_tbl[idx];
  float d0 = 0.f, d1 = 0.f, d2 = 0.f, d3 = 0.f;
#pragma unroll
  for (int l = 0; l < LDIM; l += 4) {
    float4 t = *reinterpret_cast<const float4*>(tm + l);
    float a0 = mu[l] - t.x, a1 = mu[l + 1] - t.y;
    float a2 = mu[l + 2] - t.z, a3 = mu[l + 3] - t.w;
    d0 = fmaf(a0, a0, d0); d1 = fmaf(a1, a1, d1);
    d2 = fmaf(a2, a2, d2); d3 = fmaf(a3, a3, d3);
  }
  return 0.5f * (fmaf(ps + (d0 + d1) + (d2 + d3), __expf(-tlv), tlv - logs) - (float)LDIM);
}

__global__ __launch_bounds__(256) void bsg_fb(
    const float* __restrict__ emb, const float* __restrict__ W1,
    const float* __restrict__ b1, const float* __restrict__ Wmu,
    const float* __restrict__ bmu, const float* __restrict__ Wls,
    const float* __restrict__ bls, const float* __restrict__ tm_tbl,
    const float* __restrict__ tlv_tbl, const int* __restrict__ centers,
    const int* __restrict__ contexts, const int* __restrict__ negctx,
    float* __restrict__ partials) {
  const int b = blockIdx.x * 256 + threadIdx.x;
  const int cen = centers[b];
  float ecen[D];
  const float* ep = emb + (size_t)cen * D;
#pragma unroll
  for (int f = 0; f < D; f += 2) {
    float2 v = *reinterpret_cast<const float2*>(ep + f);
    ecen[f] = v.x; ecen[f + 1] = v.y;
  }
  float z[H];
#pragma unroll
  for (int j = 0; j < H; ++j) z[j] = b1[j];
#pragma unroll
  for (int f = 0; f < D; ++f) {
    float vf = ecen[f];
#pragma unroll
    for (int j = 0; j < H; ++j) z[j] = fmaf(vf, W1[(D + f) * H + j], z[j]);
  }
  float h[H];
#pragma unroll
  for (int j = 0; j < H; ++j) h[j] = 0.f;
  for (int c = 0; c < C; ++c) {
    const float* ecp = emb + (size_t)contexts[b * C + c] * D;
    float s[H];
#pragma unroll
    for (int j = 0; j < H; ++j) s[j] = z[j];
#pragma unroll
    for (int f = 0; f < D; ++f) {
      float vf = ecp[f];
#pragma unroll
      for (int j = 0; j < H; ++j) s[j] = fmaf(vf, W1[f * H + j], s[j]);
    }
#pragma unroll
    for (int j = 0; j < H; ++j) h[j] += fmaxf(s[j], 0.f);
  }
  float mu[LDIM];
#pragma unroll
  for (int l = 0; l < LDIM; ++l) mu[l] = bmu[l];
#pragma unroll
  for (int j = 0; j < H; ++j) {
    float hj = h[j];
#pragma unroll
    for (int l = 0; l < LDIM; ++l) mu[l] = fmaf(hj, Wmu[j * LDIM + l], mu[l]);
  }
  float logs = bls[0];
#pragma unroll
  for (int j = 0; j < H; ++j) logs = fmaf(h[j], Wls[j], logs);
  float ps = __expf(logs);
  float acc = kl_term_fb(mu, ps, logs, cen, tm_tbl, tlv_tbl);
  for (int c = 0; c < C; ++c) {
    float kc = kl_term_fb(mu, ps, logs, contexts[b * C + c], tm_tbl, tlv_tbl);
    float kn = kl_term_fb(mu, ps, logs, negctx[b * C + c], tm_tbl, tlv_tbl);
    acc += fmaxf(kc - kn + 1.f, 0.f);
  }
  float vs = acc;
#pragma unroll
  for (int off = 32; off > 0; off >>= 1) vs += __shfl_down(vs, off);
  __shared__ float wsum[4];
  if ((threadIdx.x & 63) == 0) wsum[threadIdx.x >> 6] = vs;
  __syncthreads();
  if (threadIdx.x == 0) {
    float t = 0.f;
#pragma unroll
    for (int k = 0; k < 4; ++k) t += wsum[k];
    partials[blockIdx.x] = t;
  }
}
}  // namespace

extern "C" void kernel_launch(void* const* d_in, const int* in_sizes, int n_in,
                              void* d_out, int out_size, void* d_ws, size_t ws_size,
                              hipStream_t stream) {
  const float* emb     = (const float*)d_in[0];
  const float* W1      = (const float*)d_in[1];
  const float* b1      = (const float*)d_in[2];
  const float* Wmu     = (const float*)d_in[3];
  const float* bmu     = (const float*)d_in[4];
  const float* Wls     = (const float*)d_in[5];
  const float* bls     = (const float*)d_in[6];
  const float* tm      = (const float*)d_in[7];
  const float* tlv     = (const float*)d_in[8];
  const int*   centers = (const int*)d_in[9];
  const int*   ctx     = (const int*)d_in[10];
  const int*   negc    = (const int*)d_in[11];
  float* out = (float*)d_out;

  if (ws_size < WS_NEED + 1024) {
    float* partials = (float*)d_ws;
    bsg_fb<<<256, 256, 0, stream>>>(emb, W1, b1, Wmu, bmu, Wls, bls, tm, tlv,
                                    centers, ctx, negc, partials);
    bsg_reduce<<<1, 256, 0, stream>>>(partials, 256, out);
    return;
  }

  char* ws = (char*)d_ws;
  unsigned short* embB = (unsigned short*)(ws + OFF_EMB);
  unsigned char*  tmF8 = (unsigned char*)(ws + OFF_TM);
  unsigned short* w1t  = (unsigned short*)(ws + OFF_W1T);
  unsigned short* w1b  = (unsigned short*)(ws + OFF_W1B);
  unsigned short* wmuB = (unsigned short*)(ws + OFF_WMU);
  float* b1p  = (float*)(ws + OFF_B1P);
  float* bmup = (float*)(ws + OFF_BMUP);
  float* wlsp = (float*)(ws + OFF_WLSP);
  float4* tt4 = (float4*)(ws + OFF_TT);
  float* partials = (float*)(ws + OFF_PART);
  unsigned* cnt = (unsigned*)(ws + OFF_CNT);

  bsg_prep<<<1024, 256, 0, stream>>>(emb, tm, tlv, W1, Wmu, b1, bmu, Wls,
                                     embB, tmF8, tt4, w1t, w1b, wmuB, b1p, bmup,
                                     wlsp, cnt);
  bsg_main<<<B / 32, 256, 0, stream>>>(embB, tmF8, tt4, w1t, w1b, wmuB,
                                       b1p, bmup, wlsp, bls, centers, ctx, negc,
                                       partials, cnt, out);
}

// Round 15
// 73.550 us; speedup vs baseline: 4.1747x; 4.1143x over previous
//
#include <hip/hip_runtime.h>

namespace {
constexpr int V    = 50000;
constexpr int D    = 50;
constexpr int H    = 50;
constexpr int LDIM = 100;
constexpr int C    = 10;
constexpr int B    = 65536;
constexpr int NPART = (B / 32) * 4;   // 8192 partials (one per wave)

// ---- ws layout (bytes) ----
constexpr size_t OFF_EMB  = 0;                                 // [V][64] bf16
constexpr size_t OFF_TM   = OFF_EMB + (size_t)V * 64 * 2;      // [V][128] fp8 e4m3
constexpr size_t OFF_W1T  = OFF_TM + (size_t)V * 128;          // 2ks*4nt*64l*8e bf16
constexpr size_t OFF_W1B  = OFF_W1T + 2 * 4 * 64 * 8 * 2;
constexpr size_t OFF_WMU  = OFF_W1B + 2 * 4 * 64 * 8 * 2;      // 2ks*7nt*64l*8e bf16
constexpr size_t OFF_B1P  = OFF_WMU + 2 * 7 * 64 * 8 * 2;      // [64] f32
constexpr size_t OFF_BMUP = OFF_B1P + 64 * 4;                  // [128] f32
constexpr size_t OFF_WLSP = OFF_BMUP + 128 * 4;                // [64] f32
constexpr size_t OFF_TT   = OFF_WLSP + 64 * 4;                 // [V] float4 {tlv, exp(-tlv), tmsq, 0}
constexpr size_t OFF_PART = OFF_TT + (size_t)V * 16;           // [NPART] f32
constexpr size_t WS_NEED  = OFF_PART + (size_t)NPART * 4;

typedef __attribute__((ext_vector_type(8))) short short8;
typedef __attribute__((ext_vector_type(4))) float f32x4;
typedef unsigned long long ull;

__device__ __forceinline__ unsigned short f2bf(float x) {
  unsigned u = __builtin_bit_cast(unsigned, x);
  unsigned r = (u + 0x7FFFu + ((u >> 16) & 1u)) >> 16;  // RNE
  return (unsigned short)r;
}

// ================= preproc (fused): tables + tt + frags =================
__global__ __launch_bounds__(256) void bsg_prep(
    const float* __restrict__ emb, const float* __restrict__ tm,
    const float* __restrict__ tlv, const float* __restrict__ W1,
    const float* __restrict__ Wmu, const float* __restrict__ b1,
    const float* __restrict__ bmu, const float* __restrict__ Wls,
    unsigned short* __restrict__ embB, unsigned char* __restrict__ tmF8,
    float4* __restrict__ tt4, unsigned short* __restrict__ w1t,
    unsigned short* __restrict__ w1b, unsigned short* __restrict__ wmuB,
    float* __restrict__ b1p, float* __restrict__ bmup, float* __restrict__ wlsp) {
  const int EMB_T = V * 8;     // chunks of 8 bf16 over [V][64]
  const int TM_T  = V * 8;     // chunks of 16 fp8 over [V][128]
  const int stride = gridDim.x * blockDim.x;
  for (int t = blockIdx.x * blockDim.x + threadIdx.x; t < EMB_T + TM_T; t += stride) {
    if (t < EMB_T) {
      int v = t >> 3, c = t & 7, k0 = c * 8;
      unsigned short r[8];
#pragma unroll
      for (int e = 0; e < 8; ++e) {
        int k = k0 + e;
        r[e] = f2bf(k < D ? emb[(size_t)v * D + k] : 0.f);
      }
      uint4 o;
      o.x = (unsigned)r[0] | ((unsigned)r[1] << 16);
      o.y = (unsigned)r[2] | ((unsigned)r[3] << 16);
      o.z = (unsigned)r[4] | ((unsigned)r[5] << 16);
      o.w = (unsigned)r[6] | ((unsigned)r[7] << 16);
      ((uint4*)(embB + (size_t)v * 64))[c] = o;
    } else {
      int t2 = t - EMB_T;
      int v = t2 >> 3, c = t2 & 7, k0 = c * 16;
      float val[16];
#pragma unroll
      for (int e = 0; e < 16; ++e) {
        int k = k0 + e;
        val[e] = (k < LDIM) ? tm[(size_t)v * LDIM + k] : 0.f;
      }
      uint4 o;
      unsigned dw[4];
      float sq = 0.f;
#pragma unroll
      for (int j = 0; j < 4; ++j) {
        int d = __builtin_amdgcn_cvt_pk_fp8_f32(val[4 * j + 0], val[4 * j + 1], 0, false);
        d = __builtin_amdgcn_cvt_pk_fp8_f32(val[4 * j + 2], val[4 * j + 3], d, true);
        dw[j] = (unsigned)d;
        float q0 = __builtin_amdgcn_cvt_f32_fp8(d, 0);
        float q1 = __builtin_amdgcn_cvt_f32_fp8(d, 1);
        float q2 = __builtin_amdgcn_cvt_f32_fp8(d, 2);
        float q3 = __builtin_amdgcn_cvt_f32_fp8(d, 3);
        sq = fmaf(q0, q0, sq); sq = fmaf(q1, q1, sq);
        sq = fmaf(q2, q2, sq); sq = fmaf(q3, q3, sq);
      }
      o.x = dw[0]; o.y = dw[1]; o.z = dw[2]; o.w = dw[3];
      ((uint4*)(tmF8 + (size_t)v * 128))[c] = o;
#pragma unroll
      for (int off = 1; off < 8; off <<= 1) sq += __shfl_xor(sq, off);
      if (c == 0) {
        float tl = tlv[v];
        float4 q;
        q.x = tl; q.y = __expf(-tl); q.z = sq; q.w = 0.f;
        tt4[v] = q;
      }
    }
  }
  // ---- frags + bias pads (block 0 only) ----
  if (blockIdx.x == 0) {
    const int tid = threadIdx.x;
    for (int id = tid; id < 1024; id += 256) {
      int half = id >> 9, rem = id & 511;
      int ks = rem >> 8, nt = (rem >> 6) & 3, l = rem & 63;
      unsigned short r[8];
      int n = nt * 16 + (l & 15);
#pragma unroll
      for (int e = 0; e < 8; ++e) {
        int f = ks * 32 + ((l >> 4) << 3) + e;
        float v = (f < D && n < H) ? W1[(size_t)(half * D + f) * H + n] : 0.f;
        r[e] = f2bf(v);
      }
      uint4 o;
      o.x = (unsigned)r[0] | ((unsigned)r[1] << 16);
      o.y = (unsigned)r[2] | ((unsigned)r[3] << 16);
      o.z = (unsigned)r[4] | ((unsigned)r[5] << 16);
      o.w = (unsigned)r[6] | ((unsigned)r[7] << 16);
      unsigned short* dst = half ? w1b : w1t;
      ((uint4*)dst)[(ks * 4 + nt) * 64 + l] = o;
    }
    for (int id = tid; id < 896; id += 256) {
      int ks = id / 448, rem = id % 448;
      int nt = rem >> 6, l = rem & 63;
      unsigned short r[8];
      int n = nt * 16 + (l & 15);
#pragma unroll
      for (int e = 0; e < 8; ++e) {
        int j = ks * 32 + ((l >> 4) << 3) + e;
        float v = (j < H && n < LDIM) ? Wmu[(size_t)j * LDIM + n] : 0.f;
        r[e] = f2bf(v);
      }
      uint4 o;
      o.x = (unsigned)r[0] | ((unsigned)r[1] << 16);
      o.y = (unsigned)r[2] | ((unsigned)r[3] << 16);
      o.z = (unsigned)r[4] | ((unsigned)r[5] << 16);
      o.w = (unsigned)r[6] | ((unsigned)r[7] << 16);
      ((uint4*)wmuB)[(ks * 7 + nt) * 64 + l] = o;
    }
    if (tid < 64)  b1p[tid]  = (tid < H)    ? b1[tid]  : 0.f;
    if (tid < 128) bmup[tid] = (tid < LDIM) ? bmu[tid] : 0.f;
    if (tid < 64)  wlsp[tid] = (tid < H)    ? Wls[tid] : 0.f;
  }
}

// ================== fused main: MLP + KL, 32 samples/block ==================
// Exact R12 structure (40 KB LDS, (256,4), separate reduce kernel, no atomics).
// Single delta vs R12: KL steady vmcnt(9) (3 vmcnt ops per KL stage), tail 6/3/0.
__global__ __launch_bounds__(256, 4) void bsg_main(
    const unsigned short* __restrict__ embB,
    const unsigned char* __restrict__ tmF8, const float4* __restrict__ tt4,
    const unsigned short* __restrict__ w1t,
    const unsigned short* __restrict__ w1b,
    const unsigned short* __restrict__ wmuB,
    const float* __restrict__ b1p, const float* __restrict__ bmup,
    const float* __restrict__ wlsp, const float* __restrict__ bls,
    const int* __restrict__ centers, const int* __restrict__ contexts,
    const int* __restrict__ negctx, float* __restrict__ partials) {
  __shared__ __align__(16) char stg[4][4 * 2048];  // per-wave 4-slot staging ring (32 KB)
  __shared__ unsigned short hlds[32][64];          // h, bf16 (4 KB)
  __shared__ unsigned char kb[2][16][128];         // mu fp8, XOR-swizzled (4 KB)

  float* lptr = (float*)&stg[0][0];    // overlay: logs partials [2][32]  (256 B)
  float* mptr = (float*)&stg[0][256];  // overlay: musq partials [2][32]  (256 B)

  const int tid = threadIdx.x;
  const int w = tid >> 6, l = tid & 63;
  const int srow = l & 15, kc = l >> 4;
  const int st = w & 1, np = w >> 1;
  const int sblk = blockIdx.x * 32;
  const int sg = sblk + st * 16 + srow;
  const int s3 = srow & 3;

  char* kbbase = (char*)&kb[0][0][0];
  auto kb_ptr = [&](int st_, int s_, int kbyte) -> char* {
    return kbbase + st_ * 2048 + s_ * 128 + (kbyte ^ ((s_ & 7) << 4));
  };

  // zero kb pad region (latents 112..127)
  {
    int st_ = tid >> 7, rem = tid & 127;
    int s_ = rem >> 3, j = rem & 7;
    *(unsigned short*)kb_ptr(st_, s_, 112 + 2 * j) = 0;
  }

  char* myl = &stg[w][0];
  const int cofs = ((kc ^ s3) << 4);               // stage src chunk in 64B half
  const int aoff = ((kc ^ s3) << 8) + (srow << 4); // bf16 A-frag read pos (MLP)
  const int rA = ((((kc >> 1) ^ s3) * 16 + srow) * 16) + (kc & 1) * 8;   // fp8 reads (KL)
  const int rB = ((((2 + (kc >> 1)) ^ s3) * 16 + srow) * 16) + (kc & 1) * 8;

  // row ids: 0 = center, 1+c = context c (for this lane's sample)
  int rid[11];
  rid[0] = centers[sg];
#pragma unroll
  for (int c = 0; c < 10; ++c) rid[1 + c] = contexts[sg * 10 + c];

  const short8* w1tF = (const short8*)w1t;
  const short8* w1bF = (const short8*)w1b;

  short8 Bz[2][2], Bt[2][2];
#pragma unroll
  for (int n2 = 0; n2 < 2; ++n2)
#pragma unroll
    for (int ks = 0; ks < 2; ++ks) {
      Bz[n2][ks] = w1bF[(ks * 4 + 2 * np + n2) * 64 + l];
      Bt[n2][ks] = w1tF[(ks * 4 + 2 * np + n2) * 64 + l];
    }
  float b1v[2] = {b1p[(2 * np + 0) * 16 + srow], b1p[(2 * np + 1) * 16 + srow]};

  const unsigned char* embBy = (const unsigned char*)embB;

  f32x4 Z0 = {0.f, 0.f, 0.f, 0.f}, Z1 = {0.f, 0.f, 0.f, 0.f};
  f32x4 hv0 = {0.f, 0.f, 0.f, 0.f}, hv1 = {0.f, 0.f, 0.f, 0.f};

#define MLP_STAGE(T)                                                         \
  do {                                                                       \
    const unsigned char* src_ = embBy + (size_t)rid[(T)] * 128 + cofs;       \
    char* d0_ = myl + ((T) & 3) * 2048;                                      \
    __builtin_amdgcn_global_load_lds(                                        \
        (const __attribute__((address_space(1))) unsigned int*)src_,         \
        (__attribute__((address_space(3))) unsigned int*)d0_, 16, 0, 0);     \
    __builtin_amdgcn_global_load_lds(                                        \
        (const __attribute__((address_space(1))) unsigned int*)(src_ + 64),  \
        (__attribute__((address_space(3))) unsigned int*)(d0_ + 1024),       \
        16, 0, 0);                                                           \
  } while (0)

#define MLP_STEP(T, NW)                                                      \
  do {                                                                       \
    if ((T) + 3 < 11) MLP_STAGE((T) + 3);                                    \
    asm volatile("s_waitcnt vmcnt(" #NW ")" ::: "memory");                   \
    __builtin_amdgcn_sched_barrier(0);                                       \
    const char* sb_ = myl + ((T) & 3) * 2048;                                \
    short8 A0_ = *(const short8*)(sb_ + aoff);                               \
    short8 A1_ = *(const short8*)(sb_ + 1024 + aoff);                        \
    if ((T) == 0) {                                                          \
      Z0 = __builtin_amdgcn_mfma_f32_16x16x32_bf16(A0_, Bz[0][0], Z0, 0, 0, 0); \
      Z0 = __builtin_amdgcn_mfma_f32_16x16x32_bf16(A1_, Bz[0][1], Z0, 0, 0, 0); \
      Z1 = __builtin_amdgcn_mfma_f32_16x16x32_bf16(A0_, Bz[1][0], Z1, 0, 0, 0); \
      Z1 = __builtin_amdgcn_mfma_f32_16x16x32_bf16(A1_, Bz[1][1], Z1, 0, 0, 0); \
    } else {                                                                 \
      f32x4 ac0_ = {0.f, 0.f, 0.f, 0.f}, ac1_ = {0.f, 0.f, 0.f, 0.f};        \
      ac0_ = __builtin_amdgcn_mfma_f32_16x16x32_bf16(A0_, Bt[0][0], ac0_, 0, 0, 0); \
      ac0_ = __builtin_amdgcn_mfma_f32_16x16x32_bf16(A1_, Bt[0][1], ac0_, 0, 0, 0); \
      ac1_ = __builtin_amdgcn_mfma_f32_16x16x32_bf16(A0_, Bt[1][0], ac1_, 0, 0, 0); \
      ac1_ = __builtin_amdgcn_mfma_f32_16x16x32_bf16(A1_, Bt[1][1], ac1_, 0, 0, 0); \
      _Pragma("unroll")                                                      \
      for (int q = 0; q < 4; ++q) {                                          \
        hv0[q] += fmaxf(ac0_[q] + Z0[q] + b1v[0], 0.f);                      \
        hv1[q] += fmaxf(ac1_[q] + Z1[q] + b1v[1], 0.f);                      \
      }                                                                      \
    }                                                                        \
  } while (0)

  MLP_STAGE(0);
  MLP_STAGE(1);
  MLP_STAGE(2);

  MLP_STEP(0, 6); MLP_STEP(1, 6); MLP_STEP(2, 6); MLP_STEP(3, 6);
  MLP_STEP(4, 6); MLP_STEP(5, 6); MLP_STEP(6, 6); MLP_STEP(7, 6);
  MLP_STEP(8, 4); MLP_STEP(9, 2); MLP_STEP(10, 0);

#undef MLP_STEP
#undef MLP_STAGE

  __syncthreads();   // all waves done with stg -> overlay region writable

  // logs partial from C-fragments (into overlay)
  {
    float wl0 = wlsp[(2 * np + 0) * 16 + srow];
    float wl1 = wlsp[(2 * np + 1) * 16 + srow];
    float lp[4];
#pragma unroll
    for (int q = 0; q < 4; ++q) lp[q] = hv0[q] * wl0 + hv1[q] * wl1;
#pragma unroll
    for (int off = 1; off < 16; off <<= 1)
#pragma unroll
      for (int q = 0; q < 4; ++q) lp[q] += __shfl_xor(lp[q], off);
    if (srow == 0) {
#pragma unroll
      for (int q = 0; q < 4; ++q) lptr[np * 32 + st * 16 + kc * 4 + q] = lp[q];
    }
  }
#pragma unroll
  for (int q = 0; q < 4; ++q) {
    hlds[st * 16 + kc * 4 + q][(2 * np + 0) * 16 + srow] = f2bf(hv0[q]);
    hlds[st * 16 + kc * 4 + q][(2 * np + 1) * 16 + srow] = f2bf(hv1[q]);
  }
  __syncthreads();

  // ---- G3: mu = h @ Wmu + bmu -> quantize fp8 -> kb + musq (from dequant) ----
  {
    const short8* hrow = (const short8*)&hlds[st * 16 + srow][0];
    short8 Ah0 = hrow[kc], Ah1 = hrow[4 + kc];
    const short8* wmF = (const short8*)wmuB;
    f32x4 sqv = {0.f, 0.f, 0.f, 0.f};
    for (int nt = np; nt < 7; nt += 2) {
      short8 B0 = wmF[(0 * 7 + nt) * 64 + l];
      short8 B1 = wmF[(1 * 7 + nt) * 64 + l];
      f32x4 m = {0.f, 0.f, 0.f, 0.f};
      m = __builtin_amdgcn_mfma_f32_16x16x32_bf16(Ah0, B0, m, 0, 0, 0);
      m = __builtin_amdgcn_mfma_f32_16x16x32_bf16(Ah1, B1, m, 0, 0, 0);
      int lcol = nt * 16 + srow;
      float bm = bmup[lcol];
      float mv0 = m[0] + bm, mv1 = m[1] + bm, mv2 = m[2] + bm, mv3 = m[3] + bm;
      int d01 = __builtin_amdgcn_cvt_pk_fp8_f32(mv0, mv1, 0, false);
      int d23 = __builtin_amdgcn_cvt_pk_fp8_f32(mv2, mv3, 0, false);
      float q0 = __builtin_amdgcn_cvt_f32_fp8(d01, 0);
      float q1 = __builtin_amdgcn_cvt_f32_fp8(d01, 1);
      float q2 = __builtin_amdgcn_cvt_f32_fp8(d23, 0);
      float q3 = __builtin_amdgcn_cvt_f32_fp8(d23, 1);
      sqv[0] = fmaf(q0, q0, sqv[0]);
      sqv[1] = fmaf(q1, q1, sqv[1]);
      sqv[2] = fmaf(q2, q2, sqv[2]);
      sqv[3] = fmaf(q3, q3, sqv[3]);
      *(unsigned char*)kb_ptr(st, kc * 4 + 0, lcol) = (unsigned char)(d01 & 0xFF);
      *(unsigned char*)kb_ptr(st, kc * 4 + 1, lcol) = (unsigned char)((d01 >> 8) & 0xFF);
      *(unsigned char*)kb_ptr(st, kc * 4 + 2, lcol) = (unsigned char)(d23 & 0xFF);
      *(unsigned char*)kb_ptr(st, kc * 4 + 3, lcol) = (unsigned char)((d23 >> 8) & 0xFF);
    }
#pragma unroll
    for (int off = 1; off < 16; off <<= 1)
#pragma unroll
      for (int q = 0; q < 4; ++q) sqv[q] += __shfl_xor(sqv[q], off);
    if (srow == 0) {
#pragma unroll
      for (int q = 0; q < 4; ++q) mptr[np * 32 + st * 16 + kc * 4 + q] = sqv[q];
    }
  }
  __syncthreads();

  // ================= KL phase: wave w -> tile st, parity p=np =================
  const int p = np;
  const int s32 = st * 16 + srow;
  const float lg = bls[0] + lptr[s32] + lptr[32 + s32];
  const float ps = __expf(lg);
  const float msq = mptr[s32] + mptr[32 + s32];
  const bool isdiag = (kc == (srow >> 2));
  const int qd = srow & 3;

  // Bmu from kb (LDS)
  ull Bmu[4];
#pragma unroll
  for (int ks = 0; ks < 4; ++ks)
    Bmu[ks] = *(const ull*)kb_ptr(st, srow, ks * 32 + kc * 8);

  // 11 rows: center (counted only on p==0), then 5 (ctx,neg) pairs of parity p
  int kidx[11];
  kidx[0] = rid[0];
#pragma unroll
  for (int i = 0; i < 5; ++i) {
    int c = p + 2 * i;
    kidx[1 + 2 * i] = rid[1 + c];
    kidx[2 + 2 * i] = negctx[sg * 10 + c];
  }

  __syncthreads();   // overlay reads complete (barrier drains lgkmcnt) before stg reuse

  float4 ttb[4];
  float loss = 0.f, klc = 0.f;

#define KL_STAGE(T)                                                          \
  do {                                                                       \
    const unsigned char* src_ = tmF8 + (size_t)kidx[(T)] * 128 + cofs;       \
    char* d0_ = myl + ((T) & 3) * 2048;                                      \
    __builtin_amdgcn_global_load_lds(                                        \
        (const __attribute__((address_space(1))) unsigned int*)src_,         \
        (__attribute__((address_space(3))) unsigned int*)d0_, 16, 0, 0);     \
    __builtin_amdgcn_global_load_lds(                                        \
        (const __attribute__((address_space(1))) unsigned int*)(src_ + 64),  \
        (__attribute__((address_space(3))) unsigned int*)(d0_ + 1024),       \
        16, 0, 0);                                                           \
    ttb[(T) & 3] = tt4[kidx[(T)]];                                           \
  } while (0)

#define KL_STEP(T, NW)                                                       \
  do {                                                                       \
    if ((T) + 3 < 11) KL_STAGE((T) + 3);                                     \
    asm volatile("s_waitcnt vmcnt(" #NW ")" ::: "memory");                   \
    __builtin_amdgcn_sched_barrier(0);                                       \
    const char* kb_ = myl + ((T) & 3) * 2048;                                \
    ull a0_ = *(const ull*)(kb_ + rA);                                       \
    ull a1_ = *(const ull*)(kb_ + rB);                                       \
    ull a2_ = *(const ull*)(kb_ + rA + 1024);                                \
    ull a3_ = *(const ull*)(kb_ + rB + 1024);                                \
    f32x4 acc_ = {0.f, 0.f, 0.f, 0.f};                                       \
    acc_ = __builtin_amdgcn_mfma_f32_16x16x32_fp8_fp8((long)a0_, (long)Bmu[0], acc_, 0, 0, 0); \
    acc_ = __builtin_amdgcn_mfma_f32_16x16x32_fp8_fp8((long)a1_, (long)Bmu[1], acc_, 0, 0, 0); \
    acc_ = __builtin_amdgcn_mfma_f32_16x16x32_fp8_fp8((long)a2_, (long)Bmu[2], acc_, 0, 0, 0); \
    acc_ = __builtin_amdgcn_mfma_f32_16x16x32_fp8_fp8((long)a3_, (long)Bmu[3], acc_, 0, 0, 0); \
    float4 tv_ = ttb[(T) & 3];                                               \
    float dot_ = (qd & 2) ? ((qd & 1) ? acc_[3] : acc_[2])                   \
                          : ((qd & 1) ? acc_[1] : acc_[0]);                  \
    float dsum_ = msq + tv_.z - 2.f * dot_;                                  \
    float kl_ = 0.5f * (fmaf(ps + dsum_, tv_.y, tv_.x - lg) - (float)LDIM);  \
    if ((T) == 0)      loss += (isdiag && p == 0) ? kl_ : 0.f;               \
    else if ((T) & 1)  klc = kl_;                                            \
    else               loss += isdiag ? fmaxf(klc - kl_ + 1.f, 0.f) : 0.f;   \
  } while (0)

  KL_STAGE(0);
  KL_STAGE(1);
  KL_STAGE(2);

  // 3 vmcnt ops per stage (2 gload_lds + 1 tt4 load): steady depth-3 = vmcnt(9)
  KL_STEP(0, 9); KL_STEP(1, 9); KL_STEP(2, 9); KL_STEP(3, 9);
  KL_STEP(4, 9); KL_STEP(5, 9); KL_STEP(6, 9); KL_STEP(7, 9);
  KL_STEP(8, 6); KL_STEP(9, 3); KL_STEP(10, 0);

#undef KL_STEP
#undef KL_STAGE

#pragma unroll
  for (int off = 32; off > 0; off >>= 1) loss += __shfl_down(loss, off);
  if (l == 0) partials[blockIdx.x * 4 + w] = loss;
}

__global__ __launch_bounds__(256) void bsg_reduce(const float* __restrict__ partials,
                                                  int n, float* __restrict__ out) {
  double v = 0.0;
  for (int i = threadIdx.x; i < n; i += 256) v += (double)partials[i];
#pragma unroll
  for (int off = 32; off > 0; off >>= 1) v += __shfl_down(v, off);
  __shared__ double ws4[4];
  if ((threadIdx.x & 63) == 0) ws4[threadIdx.x >> 6] = v;
  __syncthreads();
  if (threadIdx.x == 0) {
    double t = 0.0;
#pragma unroll
    for (int k = 0; k < 4; ++k) t += ws4[k];
    out[0] = (float)(t / (double)B);
  }
}

// ===================== fallback (R0, known-pass) =====================
__device__ __forceinline__ float kl_term_fb(const float* mu, float ps, float logs,
                                            int idx, const float* tm_tbl,
                                            const float* tlv_tbl) {
  const float* tm = tm_tbl + (size_t)idx * LDIM;
  float tlv = tlv_tbl[idx];
  float d0 = 0.f, d1 = 0.f, d2 = 0.f, d3 = 0.f;
#pragma unroll
  for (int l = 0; l < LDIM; l += 4) {
    float4 t = *reinterpret_cast<const float4*>(tm + l);
    float a0 = mu[l] - t.x, a1 = mu[l + 1] - t.y;
    float a2 = mu[l + 2] - t.z, a3 = mu[l + 3] - t.w;
    d0 = fmaf(a0, a0, d0); d1 = fmaf(a1, a1, d1);
    d2 = fmaf(a2, a2, d2); d3 = fmaf(a3, a3, d3);
  }
  return 0.5f * (fmaf(ps + (d0 + d1) + (d2 + d3), __expf(-tlv), tlv - logs) - (float)LDIM);
}

__global__ __launch_bounds__(256) void bsg_fb(
    const float* __restrict__ emb, const float* __restrict__ W1,
    const float* __restrict__ b1, const float* __restrict__ Wmu,
    const float* __restrict__ bmu, const float* __restrict__ Wls,
    const float* __restrict__ bls, const float* __restrict__ tm_tbl,
    const float* __restrict__ tlv_tbl, const int* __restrict__ centers,
    const int* __restrict__ contexts, const int* __restrict__ negctx,
    float* __restrict__ partials) {
  const int b = blockIdx.x * 256 + threadIdx.x;
  const int cen = centers[b];
  float ecen[D];
  const float* ep = emb + (size_t)cen * D;
#pragma unroll
  for (int f = 0; f < D; f += 2) {
    float2 v = *reinterpret_cast<const float2*>(ep + f);
    ecen[f] = v.x; ecen[f + 1] = v.y;
  }
  float z[H];
#pragma unroll
  for (int j = 0; j < H; ++j) z[j] = b1[j];
#pragma unroll
  for (int f = 0; f < D; ++f) {
    float vf = ecen[f];
#pragma unroll
    for (int j = 0; j < H; ++j) z[j] = fmaf(vf, W1[(D + f) * H + j], z[j]);
  }
  float h[H];
#pragma unroll
  for (int j = 0; j < H; ++j) h[j] = 0.f;
  for (int c = 0; c < C; ++c) {
    const float* ecp = emb + (size_t)contexts[b * C + c] * D;
    float s[H];
#pragma unroll
    for (int j = 0; j < H; ++j) s[j] = z[j];
#pragma unroll
    for (int f = 0; f < D; ++f) {
      float vf = ecp[f];
#pragma unroll
      for (int j = 0; j < H; ++j) s[j] = fmaf(vf, W1[f * H + j], s[j]);
    }
#pragma unroll
    for (int j = 0; j < H; ++j) h[j] += fmaxf(s[j], 0.f);
  }
  float mu[LDIM];
#pragma unroll
  for (int l = 0; l < LDIM; ++l) mu[l] = bmu[l];
#pragma unroll
  for (int j = 0; j < H; ++j) {
    float hj = h[j];
#pragma unroll
    for (int l = 0; l < LDIM; ++l) mu[l] = fmaf(hj, Wmu[j * LDIM + l], mu[l]);
  }
  float logs = bls[0];
#pragma unroll
  for (int j = 0; j < H; ++j) logs = fmaf(h[j], Wls[j], logs);
  float ps = __expf(logs);
  float acc = kl_term_fb(mu, ps, logs, cen, tm_tbl, tlv_tbl);
  for (int c = 0; c < C; ++c) {
    float kc = kl_term_fb(mu, ps, logs, contexts[b * C + c], tm_tbl, tlv_tbl);
    float kn = kl_term_fb(mu, ps, logs, negctx[b * C + c], tm_tbl, tlv_tbl);
    acc += fmaxf(kc - kn + 1.f, 0.f);
  }
  float vs = acc;
#pragma unroll
  for (int off = 32; off > 0; off >>= 1) vs += __shfl_down(vs, off);
  __shared__ float wsum[4];
  if ((threadIdx.x & 63) == 0) wsum[threadIdx.x >> 6] = vs;
  __syncthreads();
  if (threadIdx.x == 0) {
    float t = 0.f;
#pragma unroll
    for (int k = 0; k < 4; ++k) t += wsum[k];
    partials[blockIdx.x] = t;
  }
}
}  // namespace

extern "C" void kernel_launch(void* const* d_in, const int* in_sizes, int n_in,
                              void* d_out, int out_size, void* d_ws, size_t ws_size,
                              hipStream_t stream) {
  const float* emb     = (const float*)d_in[0];
  const float* W1      = (const float*)d_in[1];
  const float* b1      = (const float*)d_in[2];
  const float* Wmu     = (const float*)d_in[3];
  const float* bmu     = (const float*)d_in[4];
  const float* Wls     = (const float*)d_in[5];
  const float* bls     = (const float*)d_in[6];
  const float* tm      = (const float*)d_in[7];
  const float* tlv     = (const float*)d_in[8];
  const int*   centers = (const int*)d_in[9];
  const int*   ctx     = (const int*)d_in[10];
  const int*   negc    = (const int*)d_in[11];
  float* out = (float*)d_out;

  if (ws_size < WS_NEED + 1024) {
    float* partials = (float*)d_ws;
    bsg_fb<<<256, 256, 0, stream>>>(emb, W1, b1, Wmu, bmu, Wls, bls, tm, tlv,
                                    centers, ctx, negc, partials);
    bsg_reduce<<<1, 256, 0, stream>>>(partials, 256, out);
    return;
  }

  char* ws = (char*)d_ws;
  unsigned short* embB = (unsigned short*)(ws + OFF_EMB);
  unsigned char*  tmF8 = (unsigned char*)(ws + OFF_TM);
  unsigned short* w1t  = (unsigned short*)(ws + OFF_W1T);
  unsigned short* w1b  = (unsigned short*)(ws + OFF_W1B);
  unsigned short* wmuB = (unsigned short*)(ws + OFF_WMU);
  float* b1p  = (float*)(ws + OFF_B1P);
  float* bmup = (float*)(ws + OFF_BMUP);
  float* wlsp = (float*)(ws + OFF_WLSP);
  float4* tt4 = (float4*)(ws + OFF_TT);
  float* partials = (float*)(ws + OFF_PART);

  bsg_prep<<<1024, 256, 0, stream>>>(emb, tm, tlv, W1, Wmu, b1, bmu, Wls,
                                     embB, tmF8, tt4, w1t, w1b, wmuB, b1p, bmup,
                                     wlsp);
  bsg_main<<<B / 32, 256, 0, stream>>>(embB, tmF8, tt4, w1t, w1b, wmuB,
                                       b1p, bmup, wlsp, bls, centers, ctx, negc,
                                       partials);
  bsg_reduce<<<1, 256, 0, stream>>>(partials, NPART, out);
}